// Round 1
// baseline (34.572 us; speedup 1.0000x reference)
//
#include <hip/hip_runtime.h>

// y[b,q] = sum_{d,f} amp[b,d,f] * sin(x_q[b,q,d] * freq[b,d,f])
//   z  : [B, 2*D*F]  (first D*F = amplitudes, second D*F = freqs), row-major [d][f]
//   x_q: [B, Q, D]
//   out: [B, Q] (trailing singleton dim flattens away)
#define ND 64
#define NF 16

__global__ __launch_bounds__(256) void sinreg_kernel(
    const float* __restrict__ z,
    const float* __restrict__ xq,
    float* __restrict__ out,
    int B, int Q) {
  const int b = blockIdx.y;
  const int q = blockIdx.x * 256 + threadIdx.x;
  if (q >= Q) return;

  // Wave-uniform coefficient pointers (addresses depend only on b,d,f ->
  // compiler emits scalar/broadcast loads; 8KB per b stays cache-resident).
  const float* __restrict__ amp = z + (size_t)b * (2 * ND * NF);
  const float* __restrict__ frq = amp + ND * NF;

  const float4* __restrict__ xrow =
      reinterpret_cast<const float4*>(xq + ((size_t)b * Q + q) * ND);

  constexpr float INV2PI = 0.15915494309189535f;  // fold radians->revolutions into x

  float acc0 = 0.f, acc1 = 0.f, acc2 = 0.f, acc3 = 0.f;

  float4 xv = xrow[0];
  #pragma unroll 1
  for (int d4 = 0; d4 < ND / 4; ++d4) {
    // software prefetch next 4 x-values one iteration ahead
    float4 xnext = xrow[(d4 + 1) & (ND / 4 - 1)];

    const float xs[4] = {xv.x * INV2PI, xv.y * INV2PI, xv.z * INV2PI, xv.w * INV2PI};
    const int dbase = d4 * 4;

    #pragma unroll
    for (int j = 0; j < 4; ++j) {
      const float xsj = xs[j];
      const float* __restrict__ fp = frq + (dbase + j) * NF;
      const float* __restrict__ ap = amp + (dbase + j) * NF;
      #pragma unroll
      for (int f = 0; f < NF; f += 4) {
        // arg in revolutions; v_fract reduces to [0,1) (period of v_sin)
        float t0 = __builtin_amdgcn_fractf(xsj * fp[f + 0]);
        float t1 = __builtin_amdgcn_fractf(xsj * fp[f + 1]);
        float t2 = __builtin_amdgcn_fractf(xsj * fp[f + 2]);
        float t3 = __builtin_amdgcn_fractf(xsj * fp[f + 3]);
        acc0 = fmaf(__builtin_amdgcn_sinf(t0), ap[f + 0], acc0);
        acc1 = fmaf(__builtin_amdgcn_sinf(t1), ap[f + 1], acc1);
        acc2 = fmaf(__builtin_amdgcn_sinf(t2), ap[f + 2], acc2);
        acc3 = fmaf(__builtin_amdgcn_sinf(t3), ap[f + 3], acc3);
      }
    }
    xv = xnext;
  }

  out[(size_t)b * Q + q] = (acc0 + acc1) + (acc2 + acc3);
}

extern "C" void kernel_launch(void* const* d_in, const int* in_sizes, int n_in,
                              void* d_out, int out_size, void* d_ws, size_t ws_size,
                              hipStream_t stream) {
  const float* z  = (const float*)d_in[0];
  const float* xq = (const float*)d_in[1];
  float* out = (float*)d_out;

  const int B = in_sizes[0] / (2 * ND * NF);   // 32
  const int Q = in_sizes[1] / (B * ND);        // 4096

  dim3 grid((Q + 255) / 256, B);
  sinreg_kernel<<<grid, 256, 0, stream>>>(z, xq, out, B, Q);
}